// Round 5
// baseline (102.747 us; speedup 1.0000x reference)
//
#include <hip/hip_runtime.h>
#include <hip/hip_bf16.h>

// B=4, T=4096, E=1024, H=64.
// d_ws: kmat bf16 [b][t][d] | qmat bf16 [b][t][d] (prescaled 0.125*log2e) |
//       vT bf16 [b][d][t]   | opart f32 [S][16384][64] | mpart,lpart f32 [S][16384]
// exp2-domain softmax; merge uses exp2f.

typedef __attribute__((ext_vector_type(8))) short short8;
typedef __attribute__((ext_vector_type(4))) short short4v;
typedef __attribute__((ext_vector_type(4))) float f32x4;
typedef __attribute__((ext_vector_type(2))) unsigned uint2v;

#define LOG2E 1.44269504f

__device__ inline short f2bf(float f) {
  union { __hip_bfloat16 h; short s; } u; u.h = __float2bfloat16(f); return u.s;
}
__device__ inline unsigned pack_bf2(float lo, float hi) {
  union { __hip_bfloat16 h; unsigned short s; } a, b;
  a.h = __float2bfloat16(lo); b.h = __float2bfloat16(hi);
  return (unsigned)a.s | ((unsigned)b.s << 16);
}
__device__ inline void gl_lds16(const short* g, short* l) {
  __builtin_amdgcn_global_load_lds(
      (const __attribute__((address_space(1))) void*)g,
      (__attribute__((address_space(3))) void*)l, 16, 0, 0);
}

#define PBM 64

// Fused projections: one x read, three GEMMs. q prescaled by 0.125*log2e;
// v written transposed vT[b][d][t]. (R2-verified structure.)
__global__ __launch_bounds__(256) void proj_fused_kernel(
    const float* __restrict__ x,
    const float* __restrict__ Wk, const float* __restrict__ Wq, const float* __restrict__ Wv,
    short* __restrict__ kout, short* __restrict__ qout, short* __restrict__ vTout)
{
  __shared__ __align__(16) short xl[PBM][72];
  __shared__ __align__(16) short wl[3][64][72];   // wl[m][n][k]

  const int tid  = threadIdx.x;
  const int w    = tid >> 6;
  const int lane = tid & 63;
  const int lr   = lane & 15;
  const int lg   = lane >> 4;
  const int rowbase = blockIdx.x * PBM;
  const float* Wm[3] = {Wk, Wq, Wv};

  f32x4 acc[3][4];
#pragma unroll
  for (int m3 = 0; m3 < 3; ++m3)
#pragma unroll
    for (int ct = 0; ct < 4; ++ct)
      acc[m3][ct] = (f32x4){0.f, 0.f, 0.f, 0.f};

  for (int kb = 0; kb < 1024; kb += 64) {
    __syncthreads();
#pragma unroll
    for (int p = 0; p < 4; ++p) {
      int idx4 = p * 256 + tid;
      int r = idx4 >> 4;
      int c = (idx4 & 15) << 2;
      float4 vv = *reinterpret_cast<const float4*>(&x[(size_t)(rowbase + r) * 1024 + kb + c]);
      short4v sv;
      sv.x = f2bf(vv.x); sv.y = f2bf(vv.y); sv.z = f2bf(vv.z); sv.w = f2bf(vv.w);
      *reinterpret_cast<short4v*>(&xl[r][c]) = sv;
    }
#pragma unroll
    for (int m3 = 0; m3 < 3; ++m3) {
      const float* W = Wm[m3];
#pragma unroll
      for (int p = 0; p < 4; ++p) {
        int idx4 = p * 256 + tid;
        int kr = idx4 >> 4;
        int c  = (idx4 & 15) << 2;
        float4 vv = *reinterpret_cast<const float4*>(&W[(size_t)(kb + kr) * 64 + c]);
        wl[m3][c + 0][kr] = f2bf(vv.x);
        wl[m3][c + 1][kr] = f2bf(vv.y);
        wl[m3][c + 2][kr] = f2bf(vv.z);
        wl[m3][c + 3][kr] = f2bf(vv.w);
      }
    }
    __syncthreads();

#pragma unroll
    for (int ks = 0; ks < 2; ++ks) {
      short8 a = *reinterpret_cast<const short8*>(&xl[16 * w + lr][ks * 32 + lg * 8]);
#pragma unroll
      for (int m3 = 0; m3 < 3; ++m3)
#pragma unroll
        for (int ct = 0; ct < 4; ++ct) {
          short8 b = *reinterpret_cast<const short8*>(&wl[m3][16 * ct + lr][ks * 32 + lg * 8]);
          acc[m3][ct] = __builtin_amdgcn_mfma_f32_16x16x32_bf16(a, b, acc[m3][ct], 0, 0, 0);
        }
    }
  }

  // epilogue. D layout: col = lr, row = lg*4+j.
  const int bb    = rowbase >> 12;
  const int tloc0 = (rowbase & 4095) + 16 * w;
#pragma unroll
  for (int ct = 0; ct < 4; ++ct) {
#pragma unroll
    for (int j = 0; j < 4; ++j) {
      int row = rowbase + 16 * w + 4 * lg + j;
      kout[(size_t)row * 64 + 16 * ct + lr] = f2bf(acc[0][ct][j]);
      qout[(size_t)row * 64 + 16 * ct + lr] = f2bf(acc[1][ct][j] * (0.125f * LOG2E));
    }
    short4v vv;
    vv.x = f2bf(acc[2][ct][0]); vv.y = f2bf(acc[2][ct][1]);
    vv.z = f2bf(acc[2][ct][2]); vv.w = f2bf(acc[2][ct][3]);
    size_t vidx = (size_t)bb * 64 * 4096 + (size_t)(16 * ct + lr) * 4096 + tloc0 + 4 * lg;
    *reinterpret_cast<short4v*>(&vTout[vidx]) = vv;
  }
}

// Per-qblock softmax + in-register P-transpose (permlane32/16_swap butterfly).
// In: s[kt16][j] = S^T[key=16kt16+4lg+j][qrow=lr] (post-QK^T, exp2 domain).
// Out: pf[ks] = B-operand fragment P[key=32ks+8lg+j][qrow=lr], j=0..7.
__device__ __forceinline__ void softmax_t(f32x4 s[4], float& m, float& l,
                                          f32x4 o[4], short8 pf[2]) {
  float pmax = s[0][0];
#pragma unroll
  for (int a = 0; a < 4; ++a)
#pragma unroll
    for (int j = 0; j < 4; ++j) pmax = fmaxf(pmax, s[a][j]);
  pmax = fmaxf(pmax, __shfl_xor(pmax, 16));
  pmax = fmaxf(pmax, __shfl_xor(pmax, 32));

  if (__any(pmax > m + 11.5f)) {       // T13 defer-max (bits)
    float mn    = fmaxf(m, pmax);
    float alpha = exp2f(m - mn);
    l *= alpha;
#pragma unroll
    for (int d = 0; d < 4; ++d) o[d] *= alpha;
    m = mn;
  }

#pragma unroll
  for (int a = 0; a < 4; ++a)
#pragma unroll
    for (int j = 0; j < 4; ++j) s[a][j] = exp2f(s[a][j] - m);
  float ps = 0.f;
#pragma unroll
  for (int a = 0; a < 4; ++a) ps += (s[a][0] + s[a][1]) + (s[a][2] + s[a][3]);
  l += ps;

  unsigned u[4][2];
#pragma unroll
  for (int a = 0; a < 4; ++a) {
    u[a][0] = pack_bf2(s[a][0], s[a][1]);
    u[a][1] = pack_bf2(s[a][2], s[a][3]);
  }
  // butterfly: swap lane-bit5 with key-bit4 (permlane32), then lane-bit4 with
  // the register axis (permlane16). Hand-traced for all lg groups.
  unsigned t[2][4];
#pragma unroll
  for (int k1 = 0; k1 < 2; ++k1)
#pragma unroll
    for (int jj = 0; jj < 2; ++jj) {
      uint2v A = __builtin_amdgcn_permlane32_swap(u[2 * k1][jj], u[2 * k1 + 1][jj], false, false);
      uint2v T = __builtin_amdgcn_permlane16_swap(A[0], A[1], false, false);
      t[k1][jj]     = T[0];
      t[k1][2 + jj] = T[1];
    }
#pragma unroll
  for (int ks = 0; ks < 2; ++ks) {
    union { unsigned u4[4]; short8 s8; } cv;
    cv.u4[0] = t[ks][0]; cv.u4[1] = t[ks][1]; cv.u4[2] = t[ks][2]; cv.u4[3] = t[ks][3];
    pf[ks] = cv.s8;
  }
}

// KV-split flash attention: block = 128 q-rows (4 waves x 32), KVBLK=64.
// K/V^T staged via global_load_lds (pre-swizzled source), double-buffered.
__global__ __launch_bounds__(256, 4) void attn_split_kernel(
    const short* __restrict__ qm, const short* __restrict__ km, const short* __restrict__ vT,
    float* __restrict__ opart, float* __restrict__ mpart, float* __restrict__ lpart,
    int S, int chunkTiles)
{
  const int nwg = 128 * S;
  int bid = (int)blockIdx.x;
  bid = (bid & 7) * (nwg >> 3) + (bid >> 3);   // bijective XCD swizzle (nwg%8==0)
  const int qidx  = bid / S;
  const int split = bid % S;
  const int b  = qidx >> 5;
  const int qt = qidx & 31;
  const int tid  = threadIdx.x;
  const int w    = tid >> 6;
  const int lane = tid & 63;
  const int lr   = lane & 15;
  const int lg   = lane >> 4;

  __shared__ __align__(16) short kl[2][4096];   // [64 keys][64 d], read-swizzled
  __shared__ __align__(16) short vl[2][4096];   // [64 d][64 keys], read-swizzled

  const short* qb    = qm + ((size_t)(b * 4096 + qt * 128 + w * 32)) * 64;
  const short* kbase = km + (size_t)b * 262144;
  const short* vbase = vT + (size_t)b * 262144;

  // global_load_lds geometry: seg s (1KB) covers rows 8s..8s+7; lane l -> row
  // 8s+(l>>3), col-chunk (l&7)*8. Source col pre-swizzled so LDS stays linear.
  const int lrow = lane >> 3;
  const int scol = ((lane & 7) * 8) ^ (lrow * 8);
  const int swr  = (lr & 7) << 3;               // read-side XOR (shorts)

  auto stage = [&](int buf, int kt) {
    const short* kp = kbase + (size_t)kt * 4096;
    gl_lds16(kp + (8 * w + lrow) * 64 + scol,       &kl[buf][w * 512]);
    gl_lds16(kp + (8 * (w + 4) + lrow) * 64 + scol, &kl[buf][(w + 4) * 512]);
    const short* vp = vbase + (size_t)kt * 64;
    gl_lds16(vp + (size_t)(8 * w + lrow) * 4096 + scol,       &vl[buf][w * 512]);
    gl_lds16(vp + (size_t)(8 * (w + 4) + lrow) * 4096 + scol, &vl[buf][(w + 4) * 512]);
  };

  short8 qf0[2], qf1[2];
#pragma unroll
  for (int ks = 0; ks < 2; ++ks) {
    qf0[ks] = *reinterpret_cast<const short8*>(&qb[lr * 64 + ks * 32 + lg * 8]);
    qf1[ks] = *reinterpret_cast<const short8*>(&qb[(16 + lr) * 64 + ks * 32 + lg * 8]);
  }

  float m0 = -3e38f, l0 = 0.f, m1 = -3e38f, l1 = 0.f;
  f32x4 o0[4], o1[4];
#pragma unroll
  for (int dt = 0; dt < 4; ++dt) {
    o0[dt] = (f32x4){0.f, 0.f, 0.f, 0.f};
    o1[dt] = (f32x4){0.f, 0.f, 0.f, 0.f};
  }

  const int kt0 = split * chunkTiles;
  stage(0, kt0);
  __syncthreads();

  for (int it = 0; it < chunkTiles; ++it) {
    const int  cur  = it & 1;
    const bool more = (it + 1) < chunkTiles;
    if (more) stage(cur ^ 1, kt0 + it + 1);   // T14: issue early, lands by barrier

    const short* klc = kl[cur];
    const short* vlc = vl[cur];

    // S^T = K Q^T for both q-blocks; K fragments read once, used twice.
    f32x4 s0[4], s1[4];
#pragma unroll
    for (int a = 0; a < 4; ++a) {
      s0[a] = (f32x4){0.f, 0.f, 0.f, 0.f};
      s1[a] = (f32x4){0.f, 0.f, 0.f, 0.f};
    }
#pragma unroll
    for (int ks = 0; ks < 2; ++ks)
#pragma unroll
      for (int kt16 = 0; kt16 < 4; ++kt16) {
        short8 kf = *reinterpret_cast<const short8*>(
            &klc[(kt16 * 16 + lr) * 64 + ((ks * 32 + lg * 8) ^ swr)]);
        s0[kt16] = __builtin_amdgcn_mfma_f32_16x16x32_bf16(kf, qf0[ks], s0[kt16], 0, 0, 0);
        s1[kt16] = __builtin_amdgcn_mfma_f32_16x16x32_bf16(kf, qf1[ks], s1[kt16], 0, 0, 0);
      }

    short8 pf0[2], pf1[2];
    softmax_t(s0, m0, l0, o0, pf0);
    softmax_t(s1, m1, l1, o1, pf1);

    // O^T += V^T P^T ; V fragments read once, used twice.
#pragma unroll
    for (int ks = 0; ks < 2; ++ks)
#pragma unroll
      for (int dt = 0; dt < 4; ++dt) {
        short8 vf = *reinterpret_cast<const short8*>(
            &vlc[(dt * 16 + lr) * 64 + ((ks * 32 + lg * 8) ^ swr)]);
        o0[dt] = __builtin_amdgcn_mfma_f32_16x16x32_bf16(vf, pf0[ks], o0[dt], 0, 0, 0);
        o1[dt] = __builtin_amdgcn_mfma_f32_16x16x32_bf16(vf, pf1[ks], o1[dt], 0, 0, 0);
      }

    if (more) __syncthreads();   // drains vmcnt: next tile fully staged
  }

  // epilogue
  l0 += __shfl_xor(l0, 16); l0 += __shfl_xor(l0, 32);
  l1 += __shfl_xor(l1, 16); l1 += __shfl_xor(l1, 32);
  const int rowg = b * 4096 + qt * 128 + w * 32 + lr;
  float* ob0 = opart + ((size_t)split * 16384 + rowg) * 64;
  float* ob1 = ob0 + 16 * 64;
#pragma unroll
  for (int dt = 0; dt < 4; ++dt) {
    *reinterpret_cast<f32x4*>(&ob0[16 * dt + 4 * lg]) = o0[dt];
    *reinterpret_cast<f32x4*>(&ob1[16 * dt + 4 * lg]) = o1[dt];
  }
  if (lane < 16) {
    mpart[split * 16384 + rowg]      = m0;
    lpart[split * 16384 + rowg]      = l0;
    mpart[split * 16384 + rowg + 16] = m1;
    lpart[split * 16384 + rowg + 16] = l1;
  }
}

__global__ __launch_bounds__(256) void merge_kernel(
    const float* __restrict__ opart, const float* __restrict__ mpart,
    const float* __restrict__ lpart, float* __restrict__ out, int S)
{
  int gid = blockIdx.x * 256 + threadIdx.x;   // over 16384*16 float4s
  int row = gid >> 4;
  int c4  = (gid & 15) << 2;
  float M = -3e38f;
  for (int s = 0; s < S; ++s) M = fmaxf(M, mpart[s * 16384 + row]);
  float denom = 0.f;
  float ax = 0.f, ay = 0.f, az = 0.f, aw = 0.f;
  for (int s = 0; s < S; ++s) {
    float wgt = exp2f(mpart[s * 16384 + row] - M);
    denom += wgt * lpart[s * 16384 + row];
    float4 op = *reinterpret_cast<const float4*>(&opart[((size_t)s * 16384 + row) * 64 + c4]);
    ax += wgt * op.x; ay += wgt * op.y; az += wgt * op.z; aw += wgt * op.w;
  }
  float inv = 1.f / denom;
  float4 r; r.x = ax * inv; r.y = ay * inv; r.z = az * inv; r.w = aw * inv;
  *reinterpret_cast<float4*>(&out[(size_t)row * 64 + c4]) = r;
}

extern "C" void kernel_launch(void* const* d_in, const int* in_sizes, int n_in,
                              void* d_out, int out_size, void* d_ws, size_t ws_size,
                              hipStream_t stream) {
  const float* x  = (const float*)d_in[0];
  const float* Wk = (const float*)d_in[1];
  const float* Wq = (const float*)d_in[2];
  const float* Wv = (const float*)d_in[3];

  const size_t MH = (size_t)16384 * 64;
  short* kmat = (short*)d_ws;
  short* qmat = kmat + MH;
  short* vTm  = qmat + MH;

  proj_fused_kernel<<<16384 / PBM, 256, 0, stream>>>(x, Wk, Wq, Wv, kmat, qmat, vTm);

  const size_t qkv_bytes = 3 * MH * sizeof(short);                 // 6 MB
  const size_t o_bytes   = MH * sizeof(float);                     // 4 MB / split
  const size_t ml_bytes  = 2 * (size_t)16384 * sizeof(float);
  int S = 8;
  while (S > 1 && qkv_bytes + (size_t)S * (o_bytes + ml_bytes) > ws_size) S >>= 1;

  float* opart = (float*)((char*)d_ws + qkv_bytes);
  float* mpart = opart + (size_t)S * MH;
  float* lpart = mpart + (size_t)S * 16384;
  attn_split_kernel<<<128 * S, 256, 0, stream>>>(qmat, kmat, vTm,
                                                 opart, mpart, lpart, S, 64 / S);
  merge_kernel<<<1024, 256, 0, stream>>>(opart, mpart, lpart, (float*)d_out, S);
}